// Round 13
// baseline (87.376 us; speedup 1.0000x reference)
//
#include <hip/hip_runtime.h>
#include <math.h>

#define IMG 256
#define NFACE 1000
#define NFP 1024               // padded face count; 4 waves x 256 faces (4 rounds)
#define NWAVE 4
#define NREP_A 5               // full-pipeline probe reps
#define NREP_B 20              // cull-only probe reps
#define EPSF 1e-8f
#define LOG2E 1.44269504088896f
#define TCUT 16.0f             // drop contributions with u < -TCUT (<= 1.44*2^-16 each)
#define ACC_BREAK 25.0f        // once all lanes of a wave exceed: its tail < 2^-25
// Tile-center cull: max_tile u <= min_k c_k(center) + 3.5*sqrt(2)*LOG2E (=7.15)
#define CULL_M (-(TCUT + 7.15f))

// Static device scratch (graph-capture safe). SoA: 9 arrays of 1024.
__device__ float g_soa[9][NFP];
__device__ float g_dbg[32 * 32 * NWAVE];   // cull-probe sink (never validated)

// Broadcast lane s's register to all lanes (uniform s -> v_readlane).
__device__ __forceinline__ float bcast(float x, int s) {
    return __uint_as_float(__builtin_amdgcn_readlane(__float_as_uint(x), s));
}
// Opaque zero in a VGPR: defeats load hoisting/CSE across measurement reps.
__device__ __forceinline__ int opqz() {
    int z = 0;
    asm volatile("" : "+v"(z));
    return z;
}

// ---------------------------------------------------------------------------
// Kernel 1: per-face edge line coefficients (log2e-scaled), SoA.
// Also zeroes out[] (block 0). Faces >= NFACE self-reject (c2 = -1e9).
// ---------------------------------------------------------------------------
__global__ __launch_bounds__(256) void k_coeff(const float* __restrict__ verts,
                                               const int* __restrict__ faces,
                                               const float* __restrict__ q,
                                               const float* __restrict__ t,
                                               const float* __restrict__ K,
                                               float* __restrict__ out) {
    int f = blockIdx.x * 256 + threadIdx.x;
    if (blockIdx.x == 0 && threadIdx.x < IMG) out[threadIdx.x] = 0.f;
    if (f >= NFP) return;

    float c[9];
    if (f < NFACE) {
        float qw = q[0], qx = q[1], qy = q[2], qz = q[3];
        float qn = sqrtf(qw * qw + qx * qx + qy * qy + qz * qz + EPSF);
        qw /= qn; qx /= qn; qy /= qn; qz /= qn;
        float R00 = 1.f - 2.f * (qy * qy + qz * qz);
        float R01 = 2.f * (qx * qy - qw * qz);
        float R02 = 2.f * (qx * qz + qw * qy);
        float R10 = 2.f * (qx * qy + qw * qz);
        float R11 = 1.f - 2.f * (qx * qx + qz * qz);
        float R12 = 2.f * (qy * qz - qw * qx);
        float R20 = 2.f * (qx * qz - qw * qy);
        float R21 = 2.f * (qy * qz + qw * qx);
        float R22 = 1.f - 2.f * (qx * qx + qy * qy);
        float tx = t[0], ty = t[1], tz = t[2];
        float K00 = K[0], K02 = K[2], K11 = K[4], K12 = K[5];

        float X[3], Y[3];
#pragma unroll
        for (int k = 0; k < 3; ++k) {
            int vi = faces[f * 3 + k];
            float vx = verts[vi * 3 + 0];
            float vy = verts[vi * 3 + 1];
            float vz = verts[vi * 3 + 2];
            float cx = R00 * vx + R01 * vy + R02 * vz + tx;
            float cy = R10 * vx + R11 * vy + R12 * vz + ty;
            float cz = R20 * vx + R21 * vy + R22 * vz + tz;
            float z = cz + EPSF;
            X[k] = K00 * cx / z + K02;
            Y[k] = K11 * cy / z + K12;
        }

        float e01x = X[1] - X[0], e01y = Y[1] - Y[0];
        float e02x = X[2] - X[0], e02y = Y[2] - Y[0];
        float area2 = e01x * e02y - e01y * e02x;
        float s = (area2 >= 0.f) ? LOG2E : -LOG2E;

#pragma unroll
        for (int k = 0; k < 3; ++k) {
            int k1 = (k + 1) % 3;
            float ex = X[k1] - X[k];
            float ey = Y[k1] - Y[k];
            float inv = s / sqrtf(ex * ex + ey * ey + EPSF);
            c[k * 3 + 0] = -ey * inv;
            c[k * 3 + 1] = ex * inv;
            c[k * 3 + 2] = (ey * X[k] - ex * Y[k]) * inv;
        }
    } else {
        c[0] = 0.f; c[1] = 0.f; c[2] = -1e9f;
        c[3] = 0.f; c[4] = 0.f; c[5] = -1e9f;
        c[6] = 0.f; c[7] = 0.f; c[8] = -1e9f;
    }

#pragma unroll
    for (int k = 0; k < 9; ++k) g_soa[k][f] = c[k];
}

// ---------------------------------------------------------------------------
// Kernel 2 (probe A): R12's fused render+loss, x NREP_A with index-laundered
// reps so Phase-A loads re-execute (R10's probe had them hoisted). Per-rep
// results are bit-identical; fmaxf keeps them live; combine+atomic runs once.
// ---------------------------------------------------------------------------
__global__ __launch_bounds__(256) void k_main(const float* __restrict__ image_ref,
                                              float* __restrict__ out) {
    const int tid = threadIdx.x;
    const int wave = tid >> 6;
    const int lane = tid & 63;
    const int x0 = blockIdx.x * 8, y0 = blockIdx.y * 8;
    const int col = x0 + (lane & 7);
    const int row = y0 + (lane >> 3);
    const float px = col + 0.5f;
    const float py = row + 0.5f;
    const float tcx = x0 + 4.0f;
    const float tcy = y0 + 4.0f;

    __shared__ float s_acc[NWAVE][64];

    float acc_keep = -1e30f;
    for (int rep = 0; rep < NREP_A; ++rep) {
        const int z = opqz();            // loads can't hoist across reps
        float acc = 0.f;
        const int wbase = wave * 256;
        for (int r = 0; r < 4; ++r) {
            const int f = wbase + r * 64 + lane + z;
            float l0 = g_soa[0][f], l1 = g_soa[1][f], l2 = g_soa[2][f];
            float l3 = g_soa[3][f], l4 = g_soa[4][f], l5 = g_soa[5][f];
            float l6 = g_soa[6][f], l7 = g_soa[7][f], l8 = g_soa[8][f];
            float m = fminf(fminf(fmaf(tcx, l0, fmaf(tcy, l1, l2)),
                                  fmaf(tcx, l3, fmaf(tcy, l4, l5))),
                            fmaf(tcx, l6, fmaf(tcy, l7, l8)));
            unsigned long long msk = __ballot(m > CULL_M);
            while (msk) {
                int s = __ffsll((unsigned long long)msk) - 1;  // uniform
                msk &= msk - 1;
                float a0 = bcast(l0, s), a1 = bcast(l1, s), a2 = bcast(l2, s);
                float b0 = bcast(l3, s), b1 = bcast(l4, s), b2 = bcast(l5, s);
                float c0 = bcast(l6, s), c1 = bcast(l7, s), c2 = bcast(l8, s);
                float u = fminf(fminf(fmaf(px, a0, fmaf(py, a1, a2)),
                                      fmaf(px, b0, fmaf(py, b1, b2))),
                                fmaf(px, c0, fmaf(py, c1, c2)));
                acc += fmaxf(u, 0.f);
                acc += __builtin_amdgcn_logf(1.f + __builtin_amdgcn_exp2f(-fabsf(u)));
            }
            if (__all(acc > ACC_BREAK)) break;
        }
        acc_keep = fmaxf(acc_keep, acc);   // identical per rep: exact, keeps live
    }

    s_acc[wave][lane] = acc_keep;
    __syncthreads();
    if (wave == 0) {
        float tot = s_acc[0][lane] + s_acc[1][lane] +
                    s_acc[2][lane] + s_acc[3][lane];
        float sil = 1.f - __builtin_amdgcn_exp2f(-tot);
        float d = sil - image_ref[row * IMG + col];
        float v = d * d;
        v += __shfl_xor(v, 1);
        v += __shfl_xor(v, 2);
        v += __shfl_xor(v, 4);
        if ((lane & 7) == 0) atomicAdd(&out[row], v * (1.f / 256.f));
    }
}

// ---------------------------------------------------------------------------
// Kernel 3 (probe B): Phase A ONLY (cull + ballot + popcount), x NREP_B,
// all 4 rounds, no early break -> clean upper bound of A's cull cost.
// Sink to g_dbg (global store: never DCE'd, not validated).
// ---------------------------------------------------------------------------
__global__ __launch_bounds__(256) void k_cullprobe() {
    const int tid = threadIdx.x;
    const int wave = tid >> 6;
    const int lane = tid & 63;
    const float tcx = blockIdx.x * 8 + 4.0f;
    const float tcy = blockIdx.y * 8 + 4.0f;

    float keep = -1e30f;
    for (int rep = 0; rep < NREP_B; ++rep) {
        const int z = opqz();
        float accb = 0.f;
        const int wbase = wave * 256;
#pragma unroll
        for (int r = 0; r < 4; ++r) {
            const int f = wbase + r * 64 + lane + z;
            float l0 = g_soa[0][f], l1 = g_soa[1][f], l2 = g_soa[2][f];
            float l3 = g_soa[3][f], l4 = g_soa[4][f], l5 = g_soa[5][f];
            float l6 = g_soa[6][f], l7 = g_soa[7][f], l8 = g_soa[8][f];
            float m = fminf(fminf(fmaf(tcx, l0, fmaf(tcy, l1, l2)),
                                  fmaf(tcx, l3, fmaf(tcy, l4, l5))),
                            fmaf(tcx, l6, fmaf(tcy, l7, l8)));
            unsigned long long msk = __ballot(m > CULL_M);
            accb += (float)__popcll(msk);
        }
        keep = fmaxf(keep, accb);
    }
    if (lane == 0) g_dbg[(blockIdx.y * 32 + blockIdx.x) * NWAVE + wave] = keep;
}

// ---------------------------------------------------------------------------
extern "C" void kernel_launch(void* const* d_in, const int* in_sizes, int n_in,
                              void* d_out, int out_size, void* d_ws, size_t ws_size,
                              hipStream_t stream) {
    const float* verts = (const float*)d_in[0];      // (1,1000,3) f32
    const int* faces = (const int*)d_in[1];          // (1,1000,3) i32
    const float* q = (const float*)d_in[2];          // (4,) f32
    const float* t = (const float*)d_in[3];          // (3,) f32
    const float* K = (const float*)d_in[4];          // (3,3) f32
    const float* image_ref = (const float*)d_in[5];  // (256,256) f32
    float* out = (float*)d_out;                      // (256,) f32

    k_coeff<<<NFP / 256, 256, 0, stream>>>(verts, faces, q, t, K, out);
    k_main<<<dim3(IMG / 8, IMG / 8), 256, 0, stream>>>(image_ref, out);
    k_cullprobe<<<dim3(IMG / 8, IMG / 8), 256, 0, stream>>>();
}

// Round 14
// 37.067 us; speedup vs baseline: 2.3572x; 2.3572x over previous
//
#include <hip/hip_runtime.h>
#include <math.h>

#define IMG 256
#define NFACE 1000
#define NFP 1024               // padded face count; 16 waves x 64 faces = 1 round each
#define NWAVE 16
#define EPSF 1e-8f
#define LOG2E 1.44269504088896f
#define TCUT 16.0f             // drop contributions with u < -TCUT (<= 1.44*2^-16 each)
// Tile-center cull: max_tile u <= min_k c_k(center) + 3.5*sqrt(2)*LOG2E (=7.15)
#define CULL_M (-(TCUT + 7.15f))

// Static device scratch (graph-capture safe). SoA: 9 arrays of 1024 floats.
// Faces >= NFACE are self-rejecting pads (c2 = -1e9 -> never survive cull).
__device__ float g_soa[9][NFP];

// Broadcast lane s's register to all lanes (uniform s -> v_readlane).
__device__ __forceinline__ float bcast(float x, int s) {
    return __uint_as_float(__builtin_amdgcn_readlane(__float_as_uint(x), s));
}

// ---------------------------------------------------------------------------
// Kernel 1: per-face edge line coefficients (log2e-scaled), SoA.
// Also zeroes out[] (block 0). Degenerate faces (repeated vertex -> zero
// edge -> c==0 everywhere, face paints an infinite line band) need no
// special case under the center-distance cull.
// ---------------------------------------------------------------------------
__global__ __launch_bounds__(256) void k_coeff(const float* __restrict__ verts,
                                               const int* __restrict__ faces,
                                               const float* __restrict__ q,
                                               const float* __restrict__ t,
                                               const float* __restrict__ K,
                                               float* __restrict__ out) {
    int f = blockIdx.x * 256 + threadIdx.x;   // grid = 4 blocks -> f in [0,1024)
    if (blockIdx.x == 0 && threadIdx.x < IMG) out[threadIdx.x] = 0.f;
    if (f >= NFP) return;

    float c[9];
    if (f < NFACE) {
        float qw = q[0], qx = q[1], qy = q[2], qz = q[3];
        float qn = sqrtf(qw * qw + qx * qx + qy * qy + qz * qz + EPSF);
        qw /= qn; qx /= qn; qy /= qn; qz /= qn;
        float R00 = 1.f - 2.f * (qy * qy + qz * qz);
        float R01 = 2.f * (qx * qy - qw * qz);
        float R02 = 2.f * (qx * qz + qw * qy);
        float R10 = 2.f * (qx * qy + qw * qz);
        float R11 = 1.f - 2.f * (qx * qx + qz * qz);
        float R12 = 2.f * (qy * qz - qw * qx);
        float R20 = 2.f * (qx * qz - qw * qy);
        float R21 = 2.f * (qy * qz + qw * qx);
        float R22 = 1.f - 2.f * (qx * qx + qy * qy);
        float tx = t[0], ty = t[1], tz = t[2];
        float K00 = K[0], K02 = K[2], K11 = K[4], K12 = K[5];

        float X[3], Y[3];
#pragma unroll
        for (int k = 0; k < 3; ++k) {
            int vi = faces[f * 3 + k];
            float vx = verts[vi * 3 + 0];
            float vy = verts[vi * 3 + 1];
            float vz = verts[vi * 3 + 2];
            float cx = R00 * vx + R01 * vy + R02 * vz + tx;
            float cy = R10 * vx + R11 * vy + R12 * vz + ty;
            float cz = R20 * vx + R21 * vy + R22 * vz + tz;
            float z = cz + EPSF;
            X[k] = K00 * cx / z + K02;
            Y[k] = K11 * cy / z + K12;
        }

        float e01x = X[1] - X[0], e01y = Y[1] - Y[0];
        float e02x = X[2] - X[0], e02y = Y[2] - Y[0];
        float area2 = e01x * e02y - e01y * e02x;
        float s = (area2 >= 0.f) ? LOG2E : -LOG2E;

#pragma unroll
        for (int k = 0; k < 3; ++k) {
            int k1 = (k + 1) % 3;
            float ex = X[k1] - X[k];
            float ey = Y[k1] - Y[k];
            float inv = s / sqrtf(ex * ex + ey * ey + EPSF);
            c[k * 3 + 0] = -ey * inv;
            c[k * 3 + 1] = ex * inv;
            c[k * 3 + 2] = (ey * X[k] - ex * Y[k]) * inv;
        }
    } else {
        c[0] = 0.f; c[1] = 0.f; c[2] = -1e9f;
        c[3] = 0.f; c[4] = 0.f; c[5] = -1e9f;
        c[6] = 0.f; c[7] = 0.f; c[8] = -1e9f;
    }

#pragma unroll
    for (int k = 0; k < 9; ++k) g_soa[k][f] = c[k];
}

// ---------------------------------------------------------------------------
// Kernel 2: fused render+loss, tail-balance shape (R13 probes: walk = ~10 of
// 11.3 us, Occupancy 17% -> worst-wave serial chain dominates). Block = one
// 8x8 tile with 1024 threads = 16 waves; each wave culls+walks only 64 faces,
// cutting the hot tile's longest serial chain ~4x vs 4-wave blocks. Grid is
// tile-swizzled (bid*37 mod 1024, bijective) so each scheduling round mixes
// hot and cold tiles per CU. 2 blocks/CU = 100% occupancy.
// ---------------------------------------------------------------------------
__global__ __launch_bounds__(1024, 2) void k_main(const float* __restrict__ image_ref,
                                                  float* __restrict__ out) {
    const int tid = threadIdx.x;
    const int wave = tid >> 6;
    const int lane = tid & 63;
    const int tile = (blockIdx.x * 37) & 1023;   // odd multiplier: bijection
    const int x0 = (tile & 31) * 8, y0 = (tile >> 5) * 8;
    const int col = x0 + (lane & 7);
    const int row = y0 + (lane >> 3);
    const float px = col + 0.5f;
    const float py = row + 0.5f;
    const float tcx = x0 + 4.0f;   // pixel centers span +0.5..+7.5
    const float tcy = y0 + 4.0f;

    __shared__ float s_acc[NWAVE][64];

    // ---- one cull round: this wave's 64 faces ----
    const int f = wave * 64 + lane;
    float l0 = g_soa[0][f], l1 = g_soa[1][f], l2 = g_soa[2][f];
    float l3 = g_soa[3][f], l4 = g_soa[4][f], l5 = g_soa[5][f];
    float l6 = g_soa[6][f], l7 = g_soa[7][f], l8 = g_soa[8][f];
    float m = fminf(fminf(fmaf(tcx, l0, fmaf(tcy, l1, l2)),
                          fmaf(tcx, l3, fmaf(tcy, l4, l5))),
                    fmaf(tcx, l6, fmaf(tcy, l7, l8)));
    unsigned long long msk = __ballot(m > CULL_M);

    // ---- register-broadcast walk of this wave's survivors ----
    float acc = 0.f;
    while (msk) {
        int s = __ffsll((unsigned long long)msk) - 1;  // uniform
        msk &= msk - 1;
        float a0 = bcast(l0, s), a1 = bcast(l1, s), a2 = bcast(l2, s);
        float b0 = bcast(l3, s), b1 = bcast(l4, s), b2 = bcast(l5, s);
        float c0 = bcast(l6, s), c1 = bcast(l7, s), c2 = bcast(l8, s);
        float u = fminf(fminf(fmaf(px, a0, fmaf(py, a1, a2)),
                              fmaf(px, b0, fmaf(py, b1, b2))),
                        fmaf(px, c0, fmaf(py, c1, c2)));
        acc += fmaxf(u, 0.f);
        acc += __builtin_amdgcn_logf(1.f + __builtin_amdgcn_exp2f(-fabsf(u)));
    }

    // ---- combine 16 waves, sil, sqdiff, row-reduce, atomic row partial ----
    s_acc[wave][lane] = acc;
    __syncthreads();
    if (wave == 0) {
        float tot = 0.f;
#pragma unroll
        for (int w = 0; w < NWAVE; ++w) tot += s_acc[w][lane];
        float sil = 1.f - __builtin_amdgcn_exp2f(-tot);
        float d = sil - image_ref[row * IMG + col];
        float v = d * d;
        v += __shfl_xor(v, 1);   // sum over the 8 cols of this tile row
        v += __shfl_xor(v, 2);
        v += __shfl_xor(v, 4);
        if ((lane & 7) == 0) atomicAdd(&out[row], v * (1.f / 256.f));
    }
}

// ---------------------------------------------------------------------------
extern "C" void kernel_launch(void* const* d_in, const int* in_sizes, int n_in,
                              void* d_out, int out_size, void* d_ws, size_t ws_size,
                              hipStream_t stream) {
    const float* verts = (const float*)d_in[0];      // (1,1000,3) f32
    const int* faces = (const int*)d_in[1];          // (1,1000,3) i32
    const float* q = (const float*)d_in[2];          // (4,) f32
    const float* t = (const float*)d_in[3];          // (3,) f32
    const float* K = (const float*)d_in[4];          // (3,3) f32
    const float* image_ref = (const float*)d_in[5];  // (256,256) f32
    float* out = (float*)d_out;                      // (256,) f32

    k_coeff<<<NFP / 256, 256, 0, stream>>>(verts, faces, q, t, K, out);
    k_main<<<1024, 1024, 0, stream>>>(image_ref, out);
}

// Round 15
// 26.785 us; speedup vs baseline: 3.2622x; 1.3839x over previous
//
#include <hip/hip_runtime.h>
#include <math.h>

#define IMG 256
#define NFACE 1000
#define NFP 1024               // padded face count; 4 waves x 256 faces (4 rounds)
#define NWAVE 4
#define CAP 320                // shared survivor-list capacity (15 KB LDS)
#define EPSF 1e-8f
#define LOG2E 1.44269504088896f
#define TCUT 16.0f             // drop contributions with u < -TCUT (<= 1.44*2^-16 each)
#define ACC_BREAK 25.0f        // wave partial acc > 25 -> its dropped tail < 2^-25
// Tile-center cull: max_tile u <= min_k c_k(center) + 3.5*sqrt(2)*LOG2E (=7.15)
#define CULL_M (-(TCUT + 7.15f))

// Static device scratch (graph-capture safe). SoA: 9 arrays of 1024 floats.
// Faces >= NFACE are self-rejecting pads (c2 = -1e9 -> never survive cull).
__device__ float g_soa[9][NFP];

__device__ __forceinline__ float bcastf(float x, int s) {
    return __uint_as_float(__builtin_amdgcn_readlane(__float_as_uint(x), s));
}

// ---------------------------------------------------------------------------
// Kernel 1: per-face edge line coefficients (log2e-scaled), SoA.
// Also zeroes out[] (block 0). Degenerate faces (repeated vertex -> zero
// edge -> c==0 everywhere, face paints an infinite line band) need no
// special case under the center-distance cull.
// ---------------------------------------------------------------------------
__global__ __launch_bounds__(256) void k_coeff(const float* __restrict__ verts,
                                               const int* __restrict__ faces,
                                               const float* __restrict__ q,
                                               const float* __restrict__ t,
                                               const float* __restrict__ K,
                                               float* __restrict__ out) {
    int f = blockIdx.x * 256 + threadIdx.x;   // grid = 4 blocks -> f in [0,1024)
    if (blockIdx.x == 0 && threadIdx.x < IMG) out[threadIdx.x] = 0.f;
    if (f >= NFP) return;

    float c[9];
    if (f < NFACE) {
        float qw = q[0], qx = q[1], qy = q[2], qz = q[3];
        float qn = sqrtf(qw * qw + qx * qx + qy * qy + qz * qz + EPSF);
        qw /= qn; qx /= qn; qy /= qn; qz /= qn;
        float R00 = 1.f - 2.f * (qy * qy + qz * qz);
        float R01 = 2.f * (qx * qy - qw * qz);
        float R02 = 2.f * (qx * qz + qw * qy);
        float R10 = 2.f * (qx * qy + qw * qz);
        float R11 = 1.f - 2.f * (qx * qx + qz * qz);
        float R12 = 2.f * (qy * qz - qw * qx);
        float R20 = 2.f * (qx * qz - qw * qy);
        float R21 = 2.f * (qy * qz + qw * qx);
        float R22 = 1.f - 2.f * (qx * qx + qy * qy);
        float tx = t[0], ty = t[1], tz = t[2];
        float K00 = K[0], K02 = K[2], K11 = K[4], K12 = K[5];

        float X[3], Y[3];
#pragma unroll
        for (int k = 0; k < 3; ++k) {
            int vi = faces[f * 3 + k];
            float vx = verts[vi * 3 + 0];
            float vy = verts[vi * 3 + 1];
            float vz = verts[vi * 3 + 2];
            float cx = R00 * vx + R01 * vy + R02 * vz + tx;
            float cy = R10 * vx + R11 * vy + R12 * vz + ty;
            float cz = R20 * vx + R21 * vy + R22 * vz + tz;
            float z = cz + EPSF;
            X[k] = K00 * cx / z + K02;
            Y[k] = K11 * cy / z + K12;
        }

        float e01x = X[1] - X[0], e01y = Y[1] - Y[0];
        float e02x = X[2] - X[0], e02y = Y[2] - Y[0];
        float area2 = e01x * e02y - e01y * e02x;
        float s = (area2 >= 0.f) ? LOG2E : -LOG2E;

#pragma unroll
        for (int k = 0; k < 3; ++k) {
            int k1 = (k + 1) % 3;
            float ex = X[k1] - X[k];
            float ey = Y[k1] - Y[k];
            float inv = s / sqrtf(ex * ex + ey * ey + EPSF);
            c[k * 3 + 0] = -ey * inv;
            c[k * 3 + 1] = ex * inv;
            c[k * 3 + 2] = (ey * X[k] - ex * Y[k]) * inv;
        }
    } else {
        c[0] = 0.f; c[1] = 0.f; c[2] = -1e9f;
        c[3] = 0.f; c[4] = 0.f; c[5] = -1e9f;
        c[6] = 0.f; c[7] = 0.f; c[8] = -1e9f;
    }

#pragma unroll
    for (int k = 0; k < 9; ++k) g_soa[k][f] = c[k];
}

// ---------------------------------------------------------------------------
// Kernel 2: fused render+loss (R14 post-mortem: readlane walk ~200cy/survivor
// serial + dropped break doubled work). New structure:
//  Phase A: wave w culls faces [w*256,(w+1)*256) in 4 rounds (all 36 loads
//           issued up-front); survivors' 9 coeffs appended from registers to
//           a BLOCK-SHARED LDS list (atomic slot alloc). Each survivor is
//           walked by exactly ONE wave - partial accs sum in the combine.
//  Phase B: wave w walks list indices i = w, w+4, ... (2-wide unroll,
//           uniform broadcast ds_read_b128 ~30cy/survivor), __all(acc>25)
//           break every pair (contributions >= 0 -> dropped tail < 2^-25).
//  Overflow (cnt > CAP, statistically never): culling wave handles the
//           excess immediately via the R12 readlane walk - still exact.
// Block = 8x8 px tile, 256 threads; LDS 16 KB -> thread-limited occupancy.
// ---------------------------------------------------------------------------
__global__ __launch_bounds__(256) void k_main(const float* __restrict__ image_ref,
                                              float* __restrict__ out) {
    const int tid = threadIdx.x;
    const int wave = tid >> 6;
    const int lane = tid & 63;
    const int x0 = blockIdx.x * 8, y0 = blockIdx.y * 8;
    const int col = x0 + (lane & 7);
    const int row = y0 + (lane >> 3);
    const float px = col + 0.5f;
    const float py = row + 0.5f;
    const float tcx = x0 + 4.0f;   // pixel centers span +0.5..+7.5
    const float tcy = y0 + 4.0f;

    __shared__ float4 s_cf[CAP * 3];     // survivor coeffs, AoS 3 x float4
    __shared__ float s_acc[NWAVE][64];
    __shared__ int s_cnt;

    if (tid == 0) s_cnt = 0;
    __syncthreads();

    // ---- Phase A: load all 4 rounds up-front (pipelined), cull, append ----
    float l[4][9];
#pragma unroll
    for (int r = 0; r < 4; ++r) {
        const int f = r * 256 + wave * 64 + lane;
#pragma unroll
        for (int k = 0; k < 9; ++k) l[r][k] = g_soa[k][f];
    }

    float acc = 0.f;   // seeded by overflow fallback (rare), then Phase B
#pragma unroll
    for (int r = 0; r < 4; ++r) {
        float m = fminf(fminf(fmaf(tcx, l[r][0], fmaf(tcy, l[r][1], l[r][2])),
                              fmaf(tcx, l[r][3], fmaf(tcy, l[r][4], l[r][5]))),
                        fmaf(tcx, l[r][6], fmaf(tcy, l[r][7], l[r][8])));
        bool hit = (m > CULL_M);
        unsigned long long msk = __ballot(hit);
        int n = __popcll(msk);
        int base = 0;
        if (lane == 0) base = atomicAdd(&s_cnt, n);
        base = __builtin_amdgcn_readlane(base, 0);
        int pos = base + __popcll(msk & ((1ull << lane) - 1ull));
        if (hit && pos < CAP) {
            s_cf[pos * 3 + 0] = make_float4(l[r][0], l[r][1], l[r][2], 0.f);
            s_cf[pos * 3 + 1] = make_float4(l[r][3], l[r][4], l[r][5], 0.f);
            s_cf[pos * 3 + 2] = make_float4(l[r][6], l[r][7], l[r][8], 0.f);
        }
        // overflow fallback: this wave walks its own excess via readlane
        unsigned long long ovm = __ballot(hit && pos >= CAP);
        while (ovm) {
            int s = __ffsll((unsigned long long)ovm) - 1;
            ovm &= ovm - 1;
            float a0 = bcastf(l[r][0], s), a1 = bcastf(l[r][1], s), a2 = bcastf(l[r][2], s);
            float b0 = bcastf(l[r][3], s), b1 = bcastf(l[r][4], s), b2 = bcastf(l[r][5], s);
            float c0 = bcastf(l[r][6], s), c1 = bcastf(l[r][7], s), c2 = bcastf(l[r][8], s);
            float u = fminf(fminf(fmaf(px, a0, fmaf(py, a1, a2)),
                                  fmaf(px, b0, fmaf(py, b1, b2))),
                            fmaf(px, c0, fmaf(py, c1, c2)));
            acc += fmaxf(u, 0.f);
            acc += __builtin_amdgcn_logf(1.f + __builtin_amdgcn_exp2f(-fabsf(u)));
        }
    }
    __syncthreads();
    const int cnt = min(s_cnt, CAP);

    // ---- Phase B: interleaved walk (wave w: i = w, w+4, ...), unroll 2 ----
    int i = wave;
    for (; i + 4 < cnt; i += 8) {
        float4 aA = s_cf[i * 3], bA = s_cf[i * 3 + 1], cA = s_cf[i * 3 + 2];
        int j = i + 4;
        float4 aB = s_cf[j * 3], bB = s_cf[j * 3 + 1], cB = s_cf[j * 3 + 2];
        float uA = fminf(fminf(fmaf(px, aA.x, fmaf(py, aA.y, aA.z)),
                               fmaf(px, bA.x, fmaf(py, bA.y, bA.z))),
                         fmaf(px, cA.x, fmaf(py, cA.y, cA.z)));
        float uB = fminf(fminf(fmaf(px, aB.x, fmaf(py, aB.y, aB.z)),
                               fmaf(px, bB.x, fmaf(py, bB.y, bB.z))),
                         fmaf(px, cB.x, fmaf(py, cB.y, cB.z)));
        acc += fmaxf(uA, 0.f) + fmaxf(uB, 0.f);
        acc += __builtin_amdgcn_logf(1.f + __builtin_amdgcn_exp2f(-fabsf(uA)));
        acc += __builtin_amdgcn_logf(1.f + __builtin_amdgcn_exp2f(-fabsf(uB)));
        if (__all(acc > ACC_BREAK)) { i = cnt; break; }  // dropped tail < 2^-25
    }
    if (i < cnt) {   // at most one remaining survivor for this wave
        float4 aA = s_cf[i * 3], bA = s_cf[i * 3 + 1], cA = s_cf[i * 3 + 2];
        float u = fminf(fminf(fmaf(px, aA.x, fmaf(py, aA.y, aA.z)),
                              fmaf(px, bA.x, fmaf(py, bA.y, bA.z))),
                        fmaf(px, cA.x, fmaf(py, cA.y, cA.z)));
        acc += fmaxf(u, 0.f);
        acc += __builtin_amdgcn_logf(1.f + __builtin_amdgcn_exp2f(-fabsf(u)));
    }

    // ---- combine waves, sil, sqdiff, row-reduce, atomic row partial ----
    s_acc[wave][lane] = acc;
    __syncthreads();
    if (wave == 0) {
        float tot = s_acc[0][lane] + s_acc[1][lane] +
                    s_acc[2][lane] + s_acc[3][lane];
        float sil = 1.f - __builtin_amdgcn_exp2f(-tot);
        float d = sil - image_ref[row * IMG + col];
        float v = d * d;
        v += __shfl_xor(v, 1);   // sum over the 8 cols of this tile row
        v += __shfl_xor(v, 2);
        v += __shfl_xor(v, 4);
        if ((lane & 7) == 0) atomicAdd(&out[row], v * (1.f / 256.f));
    }
}

// ---------------------------------------------------------------------------
extern "C" void kernel_launch(void* const* d_in, const int* in_sizes, int n_in,
                              void* d_out, int out_size, void* d_ws, size_t ws_size,
                              hipStream_t stream) {
    const float* verts = (const float*)d_in[0];      // (1,1000,3) f32
    const int* faces = (const int*)d_in[1];          // (1,1000,3) i32
    const float* q = (const float*)d_in[2];          // (4,) f32
    const float* t = (const float*)d_in[3];          // (3,) f32
    const float* K = (const float*)d_in[4];          // (3,3) f32
    const float* image_ref = (const float*)d_in[5];  // (256,256) f32
    float* out = (float*)d_out;                      // (256,) f32

    k_coeff<<<NFP / 256, 256, 0, stream>>>(verts, faces, q, t, K, out);
    k_main<<<dim3(IMG / 8, IMG / 8), 256, 0, stream>>>(image_ref, out);
}

// Round 16
// 20.718 us; speedup vs baseline: 4.2173x; 1.2928x over previous
//
#include <hip/hip_runtime.h>
#include <math.h>

#define IMG 256
#define NFACE 1000
#define NFP 1024               // padded face count; 4 waves x 256 faces (4 rounds)
#define NWAVE 4
#define EPSF 1e-8f
#define LOG2E 1.44269504088896f
#define TCUT 16.0f             // drop contributions with u < -TCUT (<= 1.44*2^-16 each)
#define ACC_BREAK 25.0f        // once all lanes of a wave exceed: its tail < 2^-25
// Tile-center cull: max_tile u <= min_k c_k(center) + 3.5*sqrt(2)*LOG2E (=7.15)
#define CULL_M (-(TCUT + 7.15f))

// Static device scratch (graph-capture safe). SoA: 9 arrays of 1024 floats.
// Faces >= NFACE are self-rejecting pads (c2 = -1e9 -> never survive cull).
__device__ float g_soa[9][NFP];

// Broadcast lane s's register to all lanes (uniform s -> v_readlane).
__device__ __forceinline__ float bcast(float x, int s) {
    return __uint_as_float(__builtin_amdgcn_readlane(__float_as_uint(x), s));
}

// ---------------------------------------------------------------------------
// Kernel 1: per-face edge line coefficients (log2e-scaled), SoA.
// Also zeroes out[] (block 0). Degenerate faces (repeated vertex -> zero
// edge -> c==0 everywhere, face paints an infinite line band) need no
// special case under the center-distance cull.
// ---------------------------------------------------------------------------
__global__ __launch_bounds__(256) void k_coeff(const float* __restrict__ verts,
                                               const int* __restrict__ faces,
                                               const float* __restrict__ q,
                                               const float* __restrict__ t,
                                               const float* __restrict__ K,
                                               float* __restrict__ out) {
    int f = blockIdx.x * 256 + threadIdx.x;   // grid = 4 blocks -> f in [0,1024)
    if (blockIdx.x == 0 && threadIdx.x < IMG) out[threadIdx.x] = 0.f;
    if (f >= NFP) return;

    float c[9];
    if (f < NFACE) {
        float qw = q[0], qx = q[1], qy = q[2], qz = q[3];
        float qn = sqrtf(qw * qw + qx * qx + qy * qy + qz * qz + EPSF);
        qw /= qn; qx /= qn; qy /= qn; qz /= qn;
        float R00 = 1.f - 2.f * (qy * qy + qz * qz);
        float R01 = 2.f * (qx * qy - qw * qz);
        float R02 = 2.f * (qx * qz + qw * qy);
        float R10 = 2.f * (qx * qy + qw * qz);
        float R11 = 1.f - 2.f * (qx * qx + qz * qz);
        float R12 = 2.f * (qy * qz - qw * qx);
        float R20 = 2.f * (qx * qz - qw * qy);
        float R21 = 2.f * (qy * qz + qw * qx);
        float R22 = 1.f - 2.f * (qx * qx + qy * qy);
        float tx = t[0], ty = t[1], tz = t[2];
        float K00 = K[0], K02 = K[2], K11 = K[4], K12 = K[5];

        float X[3], Y[3];
#pragma unroll
        for (int k = 0; k < 3; ++k) {
            int vi = faces[f * 3 + k];
            float vx = verts[vi * 3 + 0];
            float vy = verts[vi * 3 + 1];
            float vz = verts[vi * 3 + 2];
            float cx = R00 * vx + R01 * vy + R02 * vz + tx;
            float cy = R10 * vx + R11 * vy + R12 * vz + ty;
            float cz = R20 * vx + R21 * vy + R22 * vz + tz;
            float z = cz + EPSF;
            X[k] = K00 * cx / z + K02;
            Y[k] = K11 * cy / z + K12;
        }

        float e01x = X[1] - X[0], e01y = Y[1] - Y[0];
        float e02x = X[2] - X[0], e02y = Y[2] - Y[0];
        float area2 = e01x * e02y - e01y * e02x;
        float s = (area2 >= 0.f) ? LOG2E : -LOG2E;

#pragma unroll
        for (int k = 0; k < 3; ++k) {
            int k1 = (k + 1) % 3;
            float ex = X[k1] - X[k];
            float ey = Y[k1] - Y[k];
            float inv = s / sqrtf(ex * ex + ey * ey + EPSF);
            c[k * 3 + 0] = -ey * inv;
            c[k * 3 + 1] = ex * inv;
            c[k * 3 + 2] = (ey * X[k] - ex * Y[k]) * inv;
        }
    } else {
        c[0] = 0.f; c[1] = 0.f; c[2] = -1e9f;
        c[3] = 0.f; c[4] = 0.f; c[5] = -1e9f;
        c[6] = 0.f; c[7] = 0.f; c[8] = -1e9f;
    }

#pragma unroll
    for (int k = 0; k < 9; ++k) g_soa[k][f] = c[k];
}

// ---------------------------------------------------------------------------
// Kernel 2: fused render+loss. EXACTLY R12's structure (best known: per-round
// lazy loads + readlane walk + per-round break) with ONE change: the
// per-survivor softplus correction sum is replaced by a running PRODUCT,
//   sum log2(1 + 2^-|u|)  ==  log2( prod (1 + 2^-|u|) ),
// computed as p = fma(p, e, p) with e = exp2(-|u|). The exp2s are
// independent across survivors and the only loop-carried chain is a 4-cy
// fmac, collapsing the former ~60-cy u->exp->log->acc serial chain; one
// log2 per round replaces one per survivor. p <= 2^64 (64 factors <= 2)
// - no overflow; fp error ~4e-6.
// ---------------------------------------------------------------------------
__global__ __launch_bounds__(256) void k_main(const float* __restrict__ image_ref,
                                              float* __restrict__ out) {
    const int tid = threadIdx.x;
    const int wave = tid >> 6;
    const int lane = tid & 63;
    const int x0 = blockIdx.x * 8, y0 = blockIdx.y * 8;
    const int col = x0 + (lane & 7);
    const int row = y0 + (lane >> 3);
    const float px = col + 0.5f;
    const float py = row + 0.5f;
    const float tcx = x0 + 4.0f;   // pixel centers span +0.5..+7.5
    const float tcy = y0 + 4.0f;

    __shared__ float s_acc[NWAVE][64];

    float acc = 0.f;
    const int wbase = wave * 256;
    for (int r = 0; r < 4; ++r) {
        const int f = wbase + r * 64 + lane;
        float l0 = g_soa[0][f], l1 = g_soa[1][f], l2 = g_soa[2][f];
        float l3 = g_soa[3][f], l4 = g_soa[4][f], l5 = g_soa[5][f];
        float l6 = g_soa[6][f], l7 = g_soa[7][f], l8 = g_soa[8][f];
        float m = fminf(fminf(fmaf(tcx, l0, fmaf(tcy, l1, l2)),
                              fmaf(tcx, l3, fmaf(tcy, l4, l5))),
                        fmaf(tcx, l6, fmaf(tcy, l7, l8)));
        unsigned long long msk = __ballot(m > CULL_M);
        float p = 1.f;                      // running product of (1 + 2^-|u|)
        while (msk) {
            int s = __ffsll((unsigned long long)msk) - 1;  // uniform
            msk &= msk - 1;
            float a0 = bcast(l0, s), a1 = bcast(l1, s), a2 = bcast(l2, s);
            float b0 = bcast(l3, s), b1 = bcast(l4, s), b2 = bcast(l5, s);
            float c0 = bcast(l6, s), c1 = bcast(l7, s), c2 = bcast(l8, s);
            float u = fminf(fminf(fmaf(px, a0, fmaf(py, a1, a2)),
                                  fmaf(px, b0, fmaf(py, b1, b2))),
                            fmaf(px, c0, fmaf(py, c1, c2)));
            acc += fmaxf(u, 0.f);
            float e = __builtin_amdgcn_exp2f(-fabsf(u));
            p = fmaf(p, e, p);              // p *= (1 + e); independent exp2s
        }
        acc += __builtin_amdgcn_logf(p);    // one log2 per round
        if (__all(acc > ACC_BREAK)) break;  // wave's remaining tail < 2^-25
    }

    // ---- combine waves, sil, sqdiff, row-reduce, atomic row partial ----
    s_acc[wave][lane] = acc;
    __syncthreads();
    if (wave == 0) {
        float tot = s_acc[0][lane] + s_acc[1][lane] +
                    s_acc[2][lane] + s_acc[3][lane];
        float sil = 1.f - __builtin_amdgcn_exp2f(-tot);
        float d = sil - image_ref[row * IMG + col];
        float v = d * d;
        v += __shfl_xor(v, 1);   // sum over the 8 cols of this tile row
        v += __shfl_xor(v, 2);
        v += __shfl_xor(v, 4);
        if ((lane & 7) == 0) atomicAdd(&out[row], v * (1.f / 256.f));
    }
}

// ---------------------------------------------------------------------------
extern "C" void kernel_launch(void* const* d_in, const int* in_sizes, int n_in,
                              void* d_out, int out_size, void* d_ws, size_t ws_size,
                              hipStream_t stream) {
    const float* verts = (const float*)d_in[0];      // (1,1000,3) f32
    const int* faces = (const int*)d_in[1];          // (1,1000,3) i32
    const float* q = (const float*)d_in[2];          // (4,) f32
    const float* t = (const float*)d_in[3];          // (3,) f32
    const float* K = (const float*)d_in[4];          // (3,3) f32
    const float* image_ref = (const float*)d_in[5];  // (256,256) f32
    float* out = (float*)d_out;                      // (256,) f32

    k_coeff<<<NFP / 256, 256, 0, stream>>>(verts, faces, q, t, K, out);
    k_main<<<dim3(IMG / 8, IMG / 8), 256, 0, stream>>>(image_ref, out);
}